// Round 15
// baseline (4392.906 us; speedup 1.0000x reference)
//
#include <hip/hip_runtime.h>
#include <stdint.h>

#define TSTEPS 512
#define NWG 192

typedef short s8v __attribute__((ext_vector_type(8)));
typedef float f4v __attribute__((ext_vector_type(4)));
typedef unsigned long long ull;

// ---- workspace layout (bytes) ----
#define WP_BYTES  37748736ull               // packed weights bf16 (full K), fragment tiles
#define XP_BYTES 100663296ull               // packed x bf16 (GEMM B-granules)
#define GX_BYTES 402653184ull               // gx = Wx@x, bf16 [T][6144][64]
#define HS_BYTES    393216ull               // h state, 2 x 192 granules x 1KB
#define WP_OFF 0ull
#define XP_OFF 37748736ull
#define GX_OFF 138412032ull
#define HS_OFF (GX_OFF + GX_BYTES)
#define FL_OFF (HS_OFF + HS_BYTES)
#define WS_NEEDED (FL_OFF + 1024ull)        // ~516.6 MiB (proven available)

// persist LDS: 96KB partials (12 waves x 8 slots x 1KB, R12 layout) + ht
#define HT_OFF 98304
#define PLDS_TOTAL (HT_OFF + 1536)

__device__ __forceinline__ uint16_t f2bf(float f) {
  union { float f; uint32_t u; } v; v.f = f;
  uint32_t u = v.u;
  return (uint16_t)((u + 0x7fffu + ((u >> 16) & 1u)) >> 16);
}
__device__ __forceinline__ float bf2f(uint32_t u) {
  union { uint32_t u; float f; } v; v.u = u << 16;
  return v.f;
}
__device__ __forceinline__ float sigm(float x) { return 1.0f / (1.0f + __expf(-x)); }
__device__ __forceinline__ float tanh_fast(float x) {
  float e = __expf(2.0f * x);
  return 1.0f - 2.0f / (e + 1.0f);
}
__device__ __forceinline__ void gload_lds16(const void* g, void* l) {
  typedef __attribute__((address_space(1))) uint32_t g32;
  typedef __attribute__((address_space(3))) uint32_t l32;
  __builtin_amdgcn_global_load_lds((g32*)g, (l32*)l, 16, 0, 0);
}

// 16B system-coherent (LLC-direct) LOAD via inline asm: pipelined, no
// per-access waitcnt — drain manually with one s_waitcnt vmcnt(0).
// (Multi-register asm INPUTS are unsupported — R11 lesson — so the publish
// path keeps 8B atomics.)
__device__ __forceinline__ uint4 load16_sys(const void* p) {
  uint4 r;
  asm volatile("global_load_dwordx4 %0, %1, off sc0 sc1"
               : "=v"(r) : "v"(p) : "memory");
  return r;
}

// ============ prep kernels ============

// Pack W{f,i,o,c} fp32 [1536][3072] -> bf16 fragment tiles (full K).
// tile id = ((rg*96 + ks)*4 + g); lane l holds 16B =
// W_g[rg*16 + (l&15)][ks*32 + (l>>4)*8 + j], j=0..7
__global__ void pack_w(const float* __restrict__ Wf, const float* __restrict__ Wi,
                       const float* __restrict__ Wo, const float* __restrict__ Wc,
                       uint16_t* __restrict__ wp) {
  int tile = blockIdx.x * 4 + (threadIdx.x >> 6);
  int lane = threadIdx.x & 63;
  int g  = tile & 3;
  int ks = (tile >> 2) % 96;
  int rg = tile / 384;
  const float* W = (g == 0) ? Wf : (g == 1) ? Wi : (g == 2) ? Wo : Wc;
  int hr = rg * 16 + (lane & 15);
  int kk = ks * 32 + (lane >> 4) * 8;
  const float* src = W + (size_t)hr * 3072 + kk;
  uint32_t w[4];
#pragma unroll
  for (int j = 0; j < 4; ++j) {
    uint32_t lo = f2bf(src[2 * j]);
    uint32_t hi = f2bf(src[2 * j + 1]);
    w[j] = lo | (hi << 16);
  }
  *(uint4*)((char*)wp + (size_t)tile * 1024 + (size_t)lane * 16) = make_uint4(w[0], w[1], w[2], w[3]);
}

// Pack x as GEMM B-fragment granules. granule gi = n16*48 + ks;
// lane l: col n = n16*16 + (l&15) -> t=n>>6, b=n&63; k-row i = ks*32+(l>>4)*8+j
__global__ void pack_xg(const float* __restrict__ x, uint16_t* __restrict__ xg) {
  size_t gi4 = (size_t)blockIdx.x * 4 + (threadIdx.x >> 6);  // granule, < 98304
  int lane = threadIdx.x & 63;
  int n16 = (int)(gi4 / 48);
  int ks  = (int)(gi4 % 48);
  int n = n16 * 16 + (lane & 15);
  int t = n >> 6, bb = n & 63;
  int i0 = ks * 32 + (lane >> 4) * 8;
  const float* src = x + ((size_t)t * 1536 + i0) * 64 + bb;
  uint32_t w[4];
#pragma unroll
  for (int j = 0; j < 4; ++j) {
    uint32_t lo = f2bf(src[(size_t)(2 * j) * 64]);
    uint32_t hi = f2bf(src[(size_t)(2 * j + 1) * 64]);
    w[j] = lo | (hi << 16);
  }
  *(uint4*)((char*)xg + gi4 * 1024 + (size_t)lane * 16) = make_uint4(w[0], w[1], w[2], w[3]);
}

// h0 fp32 [1536][64] -> hstate[par=0] in granule layout:
// granule gr = (ch*48 + ks)*2 + cf; lane l holds 16B = bf16
// h[k = ks*32+(l>>4)*8+j][col = ch*32+cf*16+(l&15)], j=0..7
__global__ void pack_h0(const float* __restrict__ h0, uint16_t* __restrict__ hs) {
  int tg = blockIdx.x * 256 + threadIdx.x;    // < 12288
  int lane = tg & 63, gr = tg >> 6;           // gr < 192
  int cf = gr & 1, r2 = gr >> 1;
  int ks = r2 % 48, ch = r2 / 48;
  int col = ch * 32 + cf * 16 + (lane & 15);
  int k0 = ks * 32 + (lane >> 4) * 8;
  const float* src = h0 + (size_t)k0 * 64 + col;
  uint32_t w[4];
#pragma unroll
  for (int j = 0; j < 4; ++j) {
    uint32_t lo = f2bf(src[(size_t)(2 * j) * 64]);
    uint32_t hi = f2bf(src[(size_t)(2 * j + 1) * 64]);
    w[j] = lo | (hi << 16);
  }
  *(uint4*)((char*)hs + (size_t)gr * 1024 + (size_t)lane * 16) = make_uint4(w[0], w[1], w[2], w[3]);
}

// ============ gx = Wx @ X  (M=6144, N=32768, K=1536) ============
__global__ __launch_bounds__(256) void gemm_gx(const uint16_t* __restrict__ wp,
                                               const uint16_t* __restrict__ xg,
                                               uint16_t* __restrict__ gxp) {
  __shared__ char lds[32768];
  const int tid = threadIdx.x;
  const int lane = tid & 63, wave = tid >> 6;
  const int bid = blockIdx.x;
  const int mb = bid >> 8;                // 0..47
  const int nb = bid & 255;               // 0..255
  const int wm = wave >> 1, wn = wave & 1;

  const char* wpb = (const char*)wp;
  const char* xgb = (const char*)xg;
  const int g   = (mb * 8) / 96;
  const int rgb = (mb * 8) % 96;

  auto stage = [&](int ks, int buf) {
    char* Ad = lds + buf * 16384 + wave * 1024;
    char* Bd = lds + buf * 16384 + 8192 + wave * 1024;
#pragma unroll
    for (int p = 0; p < 2; ++p) {
      int l = wave + p * 4;
      size_t atile = ((size_t)(rgb + l) * 96 + 48 + ks) * 4 + g;
      gload_lds16(wpb + atile * 1024 + (size_t)lane * 16, Ad + p * 4096);
      size_t btile = (size_t)(nb * 8 + l) * 48 + ks;
      gload_lds16(xgb + btile * 1024 + (size_t)lane * 16, Bd + p * 4096);
    }
  };

  stage(0, 0);
  __syncthreads();

  f4v acc[4][4];
#pragma unroll
  for (int i = 0; i < 4; ++i)
#pragma unroll
    for (int j = 0; j < 4; ++j) acc[i][j] = f4v{0.f, 0.f, 0.f, 0.f};

  for (int ks = 0; ks < 48; ++ks) {
    int buf = ks & 1;
    if (ks < 47) stage(ks + 1, buf ^ 1);
    const char* Ab = lds + buf * 16384 + (size_t)(wm * 4) * 1024;
    const char* Bb = lds + buf * 16384 + 8192 + (size_t)(wn * 4) * 1024;
    uint4 af[4], bfr[4];
#pragma unroll
    for (int i = 0; i < 4; ++i) af[i]  = *(const uint4*)(Ab + (size_t)i * 1024 + (size_t)lane * 16);
#pragma unroll
    for (int j = 0; j < 4; ++j) bfr[j] = *(const uint4*)(Bb + (size_t)j * 1024 + (size_t)lane * 16);
#pragma unroll
    for (int i = 0; i < 4; ++i)
#pragma unroll
      for (int j = 0; j < 4; ++j)
        acc[i][j] = __builtin_amdgcn_mfma_f32_16x16x32_bf16(
            __builtin_bit_cast(s8v, af[i]), __builtin_bit_cast(s8v, bfr[j]), acc[i][j], 0, 0, 0);
    __syncthreads();
  }

#pragma unroll
  for (int i = 0; i < 4; ++i) {
    int m = (mb * 8 + wm * 4 + i) * 16 + (lane >> 4) * 4;
#pragma unroll
    for (int j = 0; j < 4; ++j) {
      int n = (nb * 8 + wn * 4 + j) * 16 + (lane & 15);
      int tt = n >> 6, bb = n & 63;
#pragma unroll
      for (int r = 0; r < 4; ++r)
        gxp[((size_t)tt * 6144 + m + r) * 64 + bb] = f2bf(acc[i][j][r]);
    }
  }
}

// ============ persistent LSTM kernel ============
// R15 = R12 with ONE change: the reduce reads uint4 (ds_read_b128) instead
// of scalar floats. 128 reduce threads (tid<128): thread (c = tid&31,
// R = tid>>5) reads src lane R*16+c15e of each slot — its 4 elements ARE
// output rows 4R..4R+3 of column c. Banks: 64 lanes x 4 dwords = 256
// accesses tiling 32 banks x 8 uniformly = hardware minimum (the old
// scalar-read pattern was an unfixable 4-way conflict: bank set 4*c15e
// closed under the +4 shifts any 16B-aligned padding can give — R14
// lesson). 96 b128 reads (~768 LDS cyc) replace 384 b32 reads (~3072).
// Each thread owns 4 outputs: gate math in regs, ht written as one 8B
// packed store, 4 out stores. All else identical to R12: 768 threads,
// K-split 12, asm 16B sc0sc1 gather + single vmcnt drain, wave0 dense
// poll + release syncthreads, wave0 publish, weights pre-issued.
__global__ __launch_bounds__(768, 3) void lstm_persist(
    const float* __restrict__ bfp, const float* __restrict__ bip,
    const float* __restrict__ bop, const float* __restrict__ bcp,
    const float* __restrict__ c0p,
    const uint16_t* wp,              // NOT restrict: may-alias hstate
    const uint16_t* __restrict__ gxp,
    uint16_t* hstate,                // NOT restrict
    int* __restrict__ flags,
    float* __restrict__ out)
{
  extern __shared__ __align__(16) char smem[];        // 96KB partials | 1.5KB ht
  uint16_t* ht = (uint16_t*)(smem + HT_OFF);          // [col][24] stride-24 bf16
  const int tid = threadIdx.x;
  const int wave = tid >> 6, lane = tid & 63;
  const int b = blockIdx.x;
  const int ch = b / 96, rg = b % 96;

  // reduce mapping (threads 0..127): col c, row-group R (rows 4R..4R+3)
  const int c = tid & 31, R = (tid >> 5) & 3;
  const bool redu = (tid < 128);
  const int cfE = c >> 4, c15e = c & 15;
  const int r4 = R * 4;
  const int hrb = rg * 16 + r4;            // valid only when redu
  const int cg = ch * 32 + c;
  const size_t soff = (size_t)(R * 16 + c15e) * 16;   // src-lane byte offset

  float cst[4] = {0.f, 0.f, 0.f, 0.f};
  float vbk[4][4];
#pragma unroll
  for (int g = 0; g < 4; ++g)
#pragma unroll
    for (int e = 0; e < 4; ++e) vbk[g][e] = 0.f;
  if (redu) {
#pragma unroll
    for (int e = 0; e < 4; ++e) {
      cst[e] = c0p[(size_t)(hrb + e) * 64 + cg];
      vbk[0][e] = bfp[hrb + e];
      vbk[1][e] = bip[hrb + e];
      vbk[2][e] = bop[hrb + e];
      vbk[3][e] = bcp[hrb + e];
    }
  }

  // per-wave weight base (16 tiles re-read each step, L2-resident, shared)
  const char* wpb = (const char*)wp
                  + ((size_t)rg * 96 + wave * 4) * 4096 + (size_t)lane * 16;
  const char* hsb = (const char*)hstate;

  for (int t = 0; t < TSTEPS; ++t) {
    const int par = t & 1;

    // ---- pre-issue loads that do NOT depend on h(t): they complete during
    //      the poll (release syncthreads drains vmcnt before s_barrier) ----
    uint32_t gxr[4][4];
#pragma unroll
    for (int g = 0; g < 4; ++g)
#pragma unroll
      for (int e = 0; e < 4; ++e) gxr[g][e] = 0;
    if (redu) {
      const uint16_t* gbase = gxp + ((size_t)t * 6144 + hrb) * 64 + cg;
#pragma unroll
      for (int g = 0; g < 4; ++g)
#pragma unroll
        for (int e = 0; e < 4; ++e)
          gxr[g][e] = gbase[((size_t)g * 1536 + e) * 64];
    }
    uint4 Ar[4][4];
#pragma unroll
    for (int q = 0; q < 4; ++q)
#pragma unroll
      for (int g = 0; g < 4; ++g)
        Ar[q][g] = *(const uint4*)(wpb + (size_t)(q * 4 + g) * 1024);
    __builtin_amdgcn_sched_barrier(0);   // pin issue order: loads first

    // ---- wave0 polls the 96 same-ch flags; barrier releases the block ----
    if (t > 0 && wave == 0) {
      const int need = t;
      const ull* fb = (const ull*)(flags + ch * 96);
      for (;;) {
        int ok = 1;
        if (lane < 48) {
          ull a = __hip_atomic_load(fb + lane, __ATOMIC_RELAXED, __HIP_MEMORY_SCOPE_SYSTEM);
          int f0 = (int)(unsigned)a, f1 = (int)(a >> 32);
          ok = (f0 >= need) & (f1 >= need);
        }
        if (__all(ok)) break;
        __builtin_amdgcn_s_sleep(1);
      }
    }
    __syncthreads();   // release: h for step t is at LLC; Ar/gx drained

    // ---- B granules: pipelined 16B sc0sc1 loads, one drain ----
    uint4 Bg[4][2];
    {
      const char* base = hsb + (((size_t)(par * 2 + ch) * 48 + wave * 4) * 2) * 1024
                             + (size_t)lane * 16;
#pragma unroll
      for (int q = 0; q < 4; ++q)
#pragma unroll
        for (int cf = 0; cf < 2; ++cf)
          Bg[q][cf] = load16_sys(base + (size_t)q * 2048 + (size_t)cf * 1024);
      asm volatile("s_waitcnt vmcnt(0)" ::: "memory");
      __builtin_amdgcn_sched_barrier(0);   // no MFMA hoisted above this point
    }

    // ---- MFMA: 32 per wave, all operands in registers ----
    f4v acc[4][2];
#pragma unroll
    for (int g = 0; g < 4; ++g)
#pragma unroll
      for (int cf = 0; cf < 2; ++cf) acc[g][cf] = f4v{0.f, 0.f, 0.f, 0.f};
#pragma unroll
    for (int q = 0; q < 4; ++q)
#pragma unroll
      for (int g = 0; g < 4; ++g)
#pragma unroll
        for (int cf = 0; cf < 2; ++cf)
          acc[g][cf] = __builtin_amdgcn_mfma_f32_16x16x32_bf16(
              __builtin_bit_cast(s8v, Ar[q][g]), __builtin_bit_cast(s8v, Bg[q][cf]),
              acc[g][cf], 0, 0, 0);

    // ---- write partials to LDS: slot (w*8+g*2+cf) x 1KB, lane*16 ----
#pragma unroll
    for (int g = 0; g < 4; ++g)
#pragma unroll
      for (int cf = 0; cf < 2; ++cf)
        *(uint4*)(smem + (((size_t)wave * 8 + g * 2 + cf) * 64 + lane) * 16)
            = __builtin_bit_cast(uint4, acc[g][cf]);
    __syncthreads();   // BARRIER A: partials complete

    // ---- reduce (threads 0..127): b128 reads, conflict-free tiling ----
    float hv[4] = {0.f, 0.f, 0.f, 0.f};
    if (redu) {
      f4v sg[4];
#pragma unroll
      for (int g = 0; g < 4; ++g) {
        const char* bp = smem + (size_t)(g * 2 + cfE) * 1024 + soff;
        f4v a0 = __builtin_bit_cast(f4v, *(const uint4*)(bp + 0 * 8192))
               + __builtin_bit_cast(f4v, *(const uint4*)(bp + 1 * 8192));
        f4v a1 = __builtin_bit_cast(f4v, *(const uint4*)(bp + 2 * 8192))
               + __builtin_bit_cast(f4v, *(const uint4*)(bp + 3 * 8192));
        f4v a2 = __builtin_bit_cast(f4v, *(const uint4*)(bp + 4 * 8192))
               + __builtin_bit_cast(f4v, *(const uint4*)(bp + 5 * 8192));
        f4v a3 = __builtin_bit_cast(f4v, *(const uint4*)(bp + 6 * 8192))
               + __builtin_bit_cast(f4v, *(const uint4*)(bp + 7 * 8192));
        f4v a4 = __builtin_bit_cast(f4v, *(const uint4*)(bp + 8 * 8192))
               + __builtin_bit_cast(f4v, *(const uint4*)(bp + 9 * 8192));
        f4v a5 = __builtin_bit_cast(f4v, *(const uint4*)(bp + 10 * 8192))
               + __builtin_bit_cast(f4v, *(const uint4*)(bp + 11 * 8192));
        sg[g] = ((a0 + a1) + (a2 + a3)) + (a4 + a5);
      }
#pragma unroll
      for (int e = 0; e < 4; ++e) {
        float pf = sg[0][e] + vbk[0][e] + bf2f(gxr[0][e]);
        float pi = sg[1][e] + vbk[1][e] + bf2f(gxr[1][e]);
        float po = sg[2][e] + vbk[2][e] + bf2f(gxr[2][e]);
        float pc = sg[3][e] + vbk[3][e] + bf2f(gxr[3][e]);
        float f = sigm(pf), ii = sigm(pi), o = sigm(po), cc = tanh_fast(pc);
        cst[e] = f * cst[e] + ii * cc;
        hv[e] = o * tanh_fast(cst[e]);
      }
      // transpose h into LDS: rows 4R..4R+3 of col c = one 8B packed store
      ull hp = (ull)f2bf(hv[0]) | ((ull)f2bf(hv[1]) << 16)
             | ((ull)f2bf(hv[2]) << 32) | ((ull)f2bf(hv[3]) << 48);
      *(ull*)&ht[c * 24 + r4] = hp;
    }
    __syncthreads();   // BARRIER B: partials consumed, ht complete

    // ---- wave 0: publish h granule-halves (system scope) + flag ----
    // out stores are issued AFTER the flag so vmcnt(0) drains only h stores.
    if (wave == 0) {
      int cf2 = lane >> 5, hh = (lane >> 4) & 1, c15 = lane & 15;
      uint4 v = *(const uint4*)(ht + (cf2 * 16 + c15) * 24 + hh * 8);
      size_t gidx = ((size_t)((par ^ 1) * 2 + ch) * 48 + (rg >> 1)) * 2 + cf2;
      int l_in = ((rg & 1) * 2 + hh) * 16 + c15;
      ull* dp = (ull*)((char*)hstate + gidx * 1024 + (size_t)l_in * 16);
      __hip_atomic_store(dp,     *(ull*)&v.x, __ATOMIC_RELAXED, __HIP_MEMORY_SCOPE_SYSTEM);
      __hip_atomic_store(dp + 1, *(ull*)&v.z, __ATOMIC_RELAXED, __HIP_MEMORY_SCOPE_SYSTEM);
      asm volatile("s_waitcnt vmcnt(0)" ::: "memory");   // h at LLC before flag
      if (lane == 0)
        __hip_atomic_store(flags + b, t + 1, __ATOMIC_RELAXED, __HIP_MEMORY_SCOPE_SYSTEM);
    }

    // ---- out stores (HBM, fire-and-forget; overlap next step's wait) ----
    if (redu) {
#pragma unroll
      for (int e = 0; e < 4; ++e)
        out[((size_t)t * 1536 + hrb + e) * 64 + cg] = hv[e];
    }
  }
}

// ============ host launcher ============
extern "C" void kernel_launch(void* const* d_in, const int* in_sizes, int n_in,
                              void* d_out, int out_size, void* d_ws, size_t ws_size,
                              hipStream_t stream) {
  (void)in_sizes; (void)n_in; (void)out_size;
  const float* x   = (const float*)d_in[0];
  const float* Wf  = (const float*)d_in[1];
  const float* bf_ = (const float*)d_in[2];
  const float* Wi  = (const float*)d_in[3];
  const float* bi_ = (const float*)d_in[4];
  const float* Wo  = (const float*)d_in[5];
  const float* bo_ = (const float*)d_in[6];
  const float* Wc  = (const float*)d_in[7];
  const float* bc_ = (const float*)d_in[8];
  const float* h0  = (const float*)d_in[9];
  const float* c0  = (const float*)d_in[10];

  if (ws_size < WS_NEEDED) return;   // diagnostic fail, not a crash

  char* ws = (char*)d_ws;
  uint16_t* wp = (uint16_t*)(ws + WP_OFF);
  uint16_t* xp = (uint16_t*)(ws + XP_OFF);
  uint16_t* gx = (uint16_t*)(ws + GX_OFF);
  uint16_t* hs = (uint16_t*)(ws + HS_OFF);
  int* flags   = (int*)(ws + FL_OFF);

  hipMemsetAsync(flags, 0, 1024, stream);
  pack_w<<<9216, 256, 0, stream>>>(Wf, Wi, Wo, Wc, wp);
  pack_xg<<<24576, 256, 0, stream>>>(x, xp);
  pack_h0<<<48, 256, 0, stream>>>(h0, hs);
  gemm_gx<<<12288, 256, 0, stream>>>(wp, xp, gx);

  hipFuncSetAttribute(reinterpret_cast<const void*>(lstm_persist),
                      hipFuncAttributeMaxDynamicSharedMemorySize, PLDS_TOTAL);
  lstm_persist<<<NWG, 768, PLDS_TOTAL, stream>>>(bf_, bi_, bo_, bc_, c0,
                                                 wp, gx, hs, flags, (float*)d_out);
}

// Round 17
// 3065.861 us; speedup vs baseline: 1.4328x; 1.4328x over previous
//
#include <hip/hip_runtime.h>
#include <stdint.h>

#define TSTEPS 512
#define NWG 192

typedef short s8v __attribute__((ext_vector_type(8)));
typedef float f4v __attribute__((ext_vector_type(4)));
typedef unsigned long long ull;

// ---- workspace layout (bytes) ----
#define WP_BYTES  37748736ull               // packed weights bf16 (full K), fragment tiles
#define XP_BYTES 100663296ull               // packed x bf16 (GEMM B-granules)
#define GX_BYTES 402653184ull               // gx = Wx@x, bf16 [T][6144][64]
#define HS_BYTES    393216ull               // h state, 2 x 192 granules x 1KB
#define WP_OFF 0ull
#define XP_OFF 37748736ull
#define GX_OFF 138412032ull
#define HS_OFF (GX_OFF + GX_BYTES)
#define FL_OFF (HS_OFF + HS_BYTES)
#define WS_NEEDED (FL_OFF + 1024ull)        // ~516.6 MiB (proven available)

// persist LDS: 96KB partials (12 waves x 8 slots x 1KB) + 1.5KB ht +
// 8.3KB stage-1 scratch. SCR_STRIDE = 1040 = 1024 DATA (64 lanes x 16B --
// R16 bug: 528 was smaller than the data, slots overlapped) + 16 pad
// (slot' shifts banks by 4; stage-2's 4 scalar reads ~4-way = ~130cyc,
// negligible).
#define HT_OFF 98304
#define SCR_OFF (HT_OFF + 1536)             // 99840
#define SCR_STRIDE 1040
#define PLDS_TOTAL (SCR_OFF + 8 * SCR_STRIDE)   // 108160 B (1 block/CU)

__device__ __forceinline__ uint16_t f2bf(float f) {
  union { float f; uint32_t u; } v; v.f = f;
  uint32_t u = v.u;
  return (uint16_t)((u + 0x7fffu + ((u >> 16) & 1u)) >> 16);
}
__device__ __forceinline__ float bf2f(uint32_t u) {
  union { uint32_t u; float f; } v; v.u = u << 16;
  return v.f;
}
__device__ __forceinline__ float sigm(float x) { return 1.0f / (1.0f + __expf(-x)); }
__device__ __forceinline__ float tanh_fast(float x) {
  float e = __expf(2.0f * x);
  return 1.0f - 2.0f / (e + 1.0f);
}
__device__ __forceinline__ void gload_lds16(const void* g, void* l) {
  typedef __attribute__((address_space(1))) uint32_t g32;
  typedef __attribute__((address_space(3))) uint32_t l32;
  __builtin_amdgcn_global_load_lds((g32*)g, (l32*)l, 16, 0, 0);
}

// 16B system-coherent (LLC-direct) LOAD via inline asm: pipelined, no
// per-access waitcnt — drain manually with one s_waitcnt vmcnt(0).
// (Multi-register asm INPUTS are unsupported — R11 lesson — so the publish
// path keeps 8B atomics.)
__device__ __forceinline__ uint4 load16_sys(const void* p) {
  uint4 r;
  asm volatile("global_load_dwordx4 %0, %1, off sc0 sc1"
               : "=v"(r) : "v"(p) : "memory");
  return r;
}

// ============ prep kernels ============

// Pack W{f,i,o,c} fp32 [1536][3072] -> bf16 fragment tiles (full K).
// tile id = ((rg*96 + ks)*4 + g); lane l holds 16B =
// W_g[rg*16 + (l&15)][ks*32 + (l>>4)*8 + j], j=0..7
__global__ void pack_w(const float* __restrict__ Wf, const float* __restrict__ Wi,
                       const float* __restrict__ Wo, const float* __restrict__ Wc,
                       uint16_t* __restrict__ wp) {
  int tile = blockIdx.x * 4 + (threadIdx.x >> 6);
  int lane = threadIdx.x & 63;
  int g  = tile & 3;
  int ks = (tile >> 2) % 96;
  int rg = tile / 384;
  const float* W = (g == 0) ? Wf : (g == 1) ? Wi : (g == 2) ? Wo : Wc;
  int hr = rg * 16 + (lane & 15);
  int kk = ks * 32 + (lane >> 4) * 8;
  const float* src = W + (size_t)hr * 3072 + kk;
  uint32_t w[4];
#pragma unroll
  for (int j = 0; j < 4; ++j) {
    uint32_t lo = f2bf(src[2 * j]);
    uint32_t hi = f2bf(src[2 * j + 1]);
    w[j] = lo | (hi << 16);
  }
  *(uint4*)((char*)wp + (size_t)tile * 1024 + (size_t)lane * 16) = make_uint4(w[0], w[1], w[2], w[3]);
}

// Pack x as GEMM B-fragment granules. granule gi = n16*48 + ks;
// lane l: col n = n16*16 + (l&15) -> t=n>>6, b=n&63; k-row i = ks*32+(l>>4)*8+j
__global__ void pack_xg(const float* __restrict__ x, uint16_t* __restrict__ xg) {
  size_t gi4 = (size_t)blockIdx.x * 4 + (threadIdx.x >> 6);  // granule, < 98304
  int lane = threadIdx.x & 63;
  int n16 = (int)(gi4 / 48);
  int ks  = (int)(gi4 % 48);
  int n = n16 * 16 + (lane & 15);
  int t = n >> 6, bb = n & 63;
  int i0 = ks * 32 + (lane >> 4) * 8;
  const float* src = x + ((size_t)t * 1536 + i0) * 64 + bb;
  uint32_t w[4];
#pragma unroll
  for (int j = 0; j < 4; ++j) {
    uint32_t lo = f2bf(src[(size_t)(2 * j) * 64]);
    uint32_t hi = f2bf(src[(size_t)(2 * j + 1) * 64]);
    w[j] = lo | (hi << 16);
  }
  *(uint4*)((char*)xg + gi4 * 1024 + (size_t)lane * 16) = make_uint4(w[0], w[1], w[2], w[3]);
}

// h0 fp32 [1536][64] -> hstate[par=0] in granule layout:
// granule gr = (ch*48 + ks)*2 + cf; lane l holds 16B = bf16
// h[k = ks*32+(l>>4)*8+j][col = ch*32+cf*16+(l&15)], j=0..7
__global__ void pack_h0(const float* __restrict__ h0, uint16_t* __restrict__ hs) {
  int tg = blockIdx.x * 256 + threadIdx.x;    // < 12288
  int lane = tg & 63, gr = tg >> 6;           // gr < 192
  int cf = gr & 1, r2 = gr >> 1;
  int ks = r2 % 48, ch = r2 / 48;
  int col = ch * 32 + cf * 16 + (lane & 15);
  int k0 = ks * 32 + (lane >> 4) * 8;
  const float* src = h0 + (size_t)k0 * 64 + col;
  uint32_t w[4];
#pragma unroll
  for (int j = 0; j < 4; ++j) {
    uint32_t lo = f2bf(src[(size_t)(2 * j) * 64]);
    uint32_t hi = f2bf(src[(size_t)(2 * j + 1) * 64]);
    w[j] = lo | (hi << 16);
  }
  *(uint4*)((char*)hs + (size_t)gr * 1024 + (size_t)lane * 16) = make_uint4(w[0], w[1], w[2], w[3]);
}

// ============ gx = Wx @ X  (M=6144, N=32768, K=1536) ============
__global__ __launch_bounds__(256) void gemm_gx(const uint16_t* __restrict__ wp,
                                               const uint16_t* __restrict__ xg,
                                               uint16_t* __restrict__ gxp) {
  __shared__ char lds[32768];
  const int tid = threadIdx.x;
  const int lane = tid & 63, wave = tid >> 6;
  const int bid = blockIdx.x;
  const int mb = bid >> 8;                // 0..47
  const int nb = bid & 255;               // 0..255
  const int wm = wave >> 1, wn = wave & 1;

  const char* wpb = (const char*)wp;
  const char* xgb = (const char*)xg;
  const int g   = (mb * 8) / 96;
  const int rgb = (mb * 8) % 96;

  auto stage = [&](int ks, int buf) {
    char* Ad = lds + buf * 16384 + wave * 1024;
    char* Bd = lds + buf * 16384 + 8192 + wave * 1024;
#pragma unroll
    for (int p = 0; p < 2; ++p) {
      int l = wave + p * 4;
      size_t atile = ((size_t)(rgb + l) * 96 + 48 + ks) * 4 + g;
      gload_lds16(wpb + atile * 1024 + (size_t)lane * 16, Ad + p * 4096);
      size_t btile = (size_t)(nb * 8 + l) * 48 + ks;
      gload_lds16(xgb + btile * 1024 + (size_t)lane * 16, Bd + p * 4096);
    }
  };

  stage(0, 0);
  __syncthreads();

  f4v acc[4][4];
#pragma unroll
  for (int i = 0; i < 4; ++i)
#pragma unroll
    for (int j = 0; j < 4; ++j) acc[i][j] = f4v{0.f, 0.f, 0.f, 0.f};

  for (int ks = 0; ks < 48; ++ks) {
    int buf = ks & 1;
    if (ks < 47) stage(ks + 1, buf ^ 1);
    const char* Ab = lds + buf * 16384 + (size_t)(wm * 4) * 1024;
    const char* Bb = lds + buf * 16384 + 8192 + (size_t)(wn * 4) * 1024;
    uint4 af[4], bfr[4];
#pragma unroll
    for (int i = 0; i < 4; ++i) af[i]  = *(const uint4*)(Ab + (size_t)i * 1024 + (size_t)lane * 16);
#pragma unroll
    for (int j = 0; j < 4; ++j) bfr[j] = *(const uint4*)(Bb + (size_t)j * 1024 + (size_t)lane * 16);
#pragma unroll
    for (int i = 0; i < 4; ++i)
#pragma unroll
      for (int j = 0; j < 4; ++j)
        acc[i][j] = __builtin_amdgcn_mfma_f32_16x16x32_bf16(
            __builtin_bit_cast(s8v, af[i]), __builtin_bit_cast(s8v, bfr[j]), acc[i][j], 0, 0, 0);
    __syncthreads();
  }

#pragma unroll
  for (int i = 0; i < 4; ++i) {
    int m = (mb * 8 + wm * 4 + i) * 16 + (lane >> 4) * 4;
#pragma unroll
    for (int j = 0; j < 4; ++j) {
      int n = (nb * 8 + wn * 4 + j) * 16 + (lane & 15);
      int tt = n >> 6, bb = n & 63;
#pragma unroll
      for (int r = 0; r < 4; ++r)
        gxp[((size_t)tt * 6144 + m + r) * 64 + bb] = f2bf(acc[i][j][r]);
    }
  }
}

// ============ persistent LSTM kernel ============
// R17 = R16 with the scratch-stride bug fixed (528 -> 1040B; each slot
// holds 64 lanes x 16B = 1024B of stage-1 output — R16's 528 made gate
// slots overlap, absmax 0.53). Structure: TWO-STAGE conflict-free reduce.
// Stage 1: 512 threads (gS = tid>>7, RS = (tid>>5)&3, cS = tid&31) sum
// their gate's 12 wave-partials with 12 ds_read_b128 (uniform bank tiling,
// measured conflict-free in R15) -> one f4v into scratch. Stage 2: 512
// threads in R12's (c,rr) mapping read 4 scalars (1/gate) from scratch,
// gate math, ht store, out store. All else identical to R12 (proven best):
// 768 threads / 12 waves / 3 per SIMD, K-split 12, asm 16B sc0sc1 gather +
// single vmcnt drain, wave0 dense poll + release syncthreads, wave0
// publish, weights pre-issued from wp before the poll.
__global__ __launch_bounds__(768, 3) void lstm_persist(
    const float* __restrict__ bfp, const float* __restrict__ bip,
    const float* __restrict__ bop, const float* __restrict__ bcp,
    const float* __restrict__ c0p,
    const uint16_t* wp,              // NOT restrict: may-alias hstate
    const uint16_t* __restrict__ gxp,
    uint16_t* hstate,                // NOT restrict
    int* __restrict__ flags,
    float* __restrict__ out)
{
  extern __shared__ __align__(16) char smem[];   // partials | ht | scratch
  uint16_t* ht = (uint16_t*)(smem + HT_OFF);     // [col][24] stride-24 bf16
  const int tid = threadIdx.x;
  const int wave = tid >> 6, lane = tid & 63;
  const int b = blockIdx.x;
  const int ch = b / 96, rg = b % 96;

  // stage-2 / epilogue mapping (threads 0..511): 16 rows x 32 cols
  const int c = tid & 31, rr = (tid >> 5) & 15;
  const int hr = rg * 16 + rr;
  const int cg = ch * 32 + c;
  const int cfE = c >> 4, c15e = c & 15;
  const bool epi = (tid < 512);
  // stage-2 scratch read offset (within slot): src_lane*16 + elem*4
  const size_t s2off = (size_t)((rr >> 2) * 16 + c15e) * 16 + (size_t)(rr & 3) * 4;

  // stage-1 mapping (threads 0..511): gate gS, row-group RS, col cS
  const int gS = (tid >> 7) & 3, RS = (tid >> 5) & 3, cS = tid & 31;
  const int slotp = gS * 2 + (cS >> 4);                 // 0..7
  const size_t s1off = (size_t)(RS * 16 + (cS & 15)) * 16;

  float cst = c0p[(size_t)hr * 64 + cg];
  const float vb[4] = {bfp[hr], bip[hr], bop[hr], bcp[hr]};

  // per-wave weight base (16 tiles re-read each step, L2-resident, shared)
  const char* wpb = (const char*)wp
                  + ((size_t)rg * 96 + wave * 4) * 4096 + (size_t)lane * 16;
  const char* hsb = (const char*)hstate;

  for (int t = 0; t < TSTEPS; ++t) {
    const int par = t & 1;

    // ---- pre-issue loads that do NOT depend on h(t): they complete during
    //      the poll (release syncthreads drains vmcnt before s_barrier) ----
    uint32_t gxr[4] = {0, 0, 0, 0};
    if (epi) {
      const uint16_t* gbase = gxp + ((size_t)t * 6144 + hr) * 64 + cg;
#pragma unroll
      for (int g = 0; g < 4; ++g)
        gxr[g] = gbase[(size_t)g * 1536 * 64];
    }
    uint4 Ar[4][4];
#pragma unroll
    for (int q = 0; q < 4; ++q)
#pragma unroll
      for (int g = 0; g < 4; ++g)
        Ar[q][g] = *(const uint4*)(wpb + (size_t)(q * 4 + g) * 1024);
    __builtin_amdgcn_sched_barrier(0);   // pin issue order: loads first

    // ---- wave0 polls the 96 same-ch flags; barrier releases the block ----
    if (t > 0 && wave == 0) {
      const int need = t;
      const ull* fb = (const ull*)(flags + ch * 96);
      for (;;) {
        int ok = 1;
        if (lane < 48) {
          ull a = __hip_atomic_load(fb + lane, __ATOMIC_RELAXED, __HIP_MEMORY_SCOPE_SYSTEM);
          int f0 = (int)(unsigned)a, f1 = (int)(a >> 32);
          ok = (f0 >= need) & (f1 >= need);
        }
        if (__all(ok)) break;
        __builtin_amdgcn_s_sleep(1);
      }
    }
    __syncthreads();   // release: h for step t is at LLC; Ar/gx drained

    // ---- B granules: pipelined 16B sc0sc1 loads, one drain ----
    uint4 Bg[4][2];
    {
      const char* base = hsb + (((size_t)(par * 2 + ch) * 48 + wave * 4) * 2) * 1024
                             + (size_t)lane * 16;
#pragma unroll
      for (int q = 0; q < 4; ++q)
#pragma unroll
        for (int cf = 0; cf < 2; ++cf)
          Bg[q][cf] = load16_sys(base + (size_t)q * 2048 + (size_t)cf * 1024);
      asm volatile("s_waitcnt vmcnt(0)" ::: "memory");
      __builtin_amdgcn_sched_barrier(0);   // no MFMA hoisted above this point
    }

    // ---- MFMA: 32 per wave, all operands in registers ----
    f4v acc[4][2];
#pragma unroll
    for (int g = 0; g < 4; ++g)
#pragma unroll
      for (int cf = 0; cf < 2; ++cf) acc[g][cf] = f4v{0.f, 0.f, 0.f, 0.f};
#pragma unroll
    for (int q = 0; q < 4; ++q)
#pragma unroll
      for (int g = 0; g < 4; ++g)
#pragma unroll
        for (int cf = 0; cf < 2; ++cf)
          acc[g][cf] = __builtin_amdgcn_mfma_f32_16x16x32_bf16(
              __builtin_bit_cast(s8v, Ar[q][g]), __builtin_bit_cast(s8v, Bg[q][cf]),
              acc[g][cf], 0, 0, 0);

    // ---- write partials to LDS: slot (w*8+g*2+cf) x 1KB, lane*16 ----
#pragma unroll
    for (int g = 0; g < 4; ++g)
#pragma unroll
      for (int cf = 0; cf < 2; ++cf)
        *(uint4*)(smem + (((size_t)wave * 8 + g * 2 + cf) * 64 + lane) * 16)
            = __builtin_bit_cast(uint4, acc[g][cf]);
    __syncthreads();   // BARRIER A: partials complete

    // ---- stage 1 (threads 0..511): b128 tree over the 12 wave-partials ----
    if (epi) {
      const char* bp = smem + (size_t)slotp * 1024 + s1off;
      f4v a0 = __builtin_bit_cast(f4v, *(const uint4*)(bp + 0 * 8192))
             + __builtin_bit_cast(f4v, *(const uint4*)(bp + 1 * 8192));
      f4v a1 = __builtin_bit_cast(f4v, *(const uint4*)(bp + 2 * 8192))
             + __builtin_bit_cast(f4v, *(const uint4*)(bp + 3 * 8192));
      f4v a2 = __builtin_bit_cast(f4v, *(const uint4*)(bp + 4 * 8192))
             + __builtin_bit_cast(f4v, *(const uint4*)(bp + 5 * 8192));
      f4v a3 = __builtin_bit_cast(f4v, *(const uint4*)(bp + 6 * 8192))
             + __builtin_bit_cast(f4v, *(const uint4*)(bp + 7 * 8192));
      f4v a4 = __builtin_bit_cast(f4v, *(const uint4*)(bp + 8 * 8192))
             + __builtin_bit_cast(f4v, *(const uint4*)(bp + 9 * 8192));
      f4v a5 = __builtin_bit_cast(f4v, *(const uint4*)(bp + 10 * 8192))
             + __builtin_bit_cast(f4v, *(const uint4*)(bp + 11 * 8192));
      f4v red = ((a0 + a1) + (a2 + a3)) + (a4 + a5);
      *(uint4*)(smem + SCR_OFF + (size_t)slotp * SCR_STRIDE + s1off)
          = __builtin_bit_cast(uint4, red);
    }
    __syncthreads();   // BARRIER A2: scratch complete

    // ---- stage 2 + gates epilogue (threads 0..511, R12 mapping) ----
    float hv = 0.0f;
    if (epi) {
      float s[4];
#pragma unroll
      for (int g = 0; g < 4; ++g)
        s[g] = *(const float*)(smem + SCR_OFF
                               + (size_t)(g * 2 + cfE) * SCR_STRIDE + s2off);
      float pf = s[0] + vb[0] + bf2f(gxr[0]);
      float pi = s[1] + vb[1] + bf2f(gxr[1]);
      float po = s[2] + vb[2] + bf2f(gxr[2]);
      float pc = s[3] + vb[3] + bf2f(gxr[3]);
      float f = sigm(pf), ii = sigm(pi), o = sigm(po), cc = tanh_fast(pc);
      cst = f * cst + ii * cc;
      hv = o * tanh_fast(cst);
      // transpose h into LDS (stride-24 bf16)
      ht[c * 24 + rr] = f2bf(hv);
    }
    __syncthreads();   // BARRIER B: scratch consumed, ht complete

    // ---- wave 0: publish h granule-halves (system scope) + flag ----
    // out stores are issued AFTER the flag so vmcnt(0) drains only h stores.
    if (wave == 0) {
      int cf2 = lane >> 5, hh = (lane >> 4) & 1, c15 = lane & 15;
      uint4 v = *(const uint4*)(ht + (cf2 * 16 + c15) * 24 + hh * 8);
      size_t gidx = ((size_t)((par ^ 1) * 2 + ch) * 48 + (rg >> 1)) * 2 + cf2;
      int l_in = ((rg & 1) * 2 + hh) * 16 + c15;
      ull* dp = (ull*)((char*)hstate + gidx * 1024 + (size_t)l_in * 16);
      __hip_atomic_store(dp,     *(ull*)&v.x, __ATOMIC_RELAXED, __HIP_MEMORY_SCOPE_SYSTEM);
      __hip_atomic_store(dp + 1, *(ull*)&v.z, __ATOMIC_RELAXED, __HIP_MEMORY_SCOPE_SYSTEM);
      asm volatile("s_waitcnt vmcnt(0)" ::: "memory");   // h at LLC before flag
      if (lane == 0)
        __hip_atomic_store(flags + b, t + 1, __ATOMIC_RELAXED, __HIP_MEMORY_SCOPE_SYSTEM);
    }

    // ---- out store (HBM, fire-and-forget; overlaps next step's wait) ----
    if (epi)
      out[((size_t)t * 1536 + hr) * 64 + cg] = hv;
  }
}

// ============ host launcher ============
extern "C" void kernel_launch(void* const* d_in, const int* in_sizes, int n_in,
                              void* d_out, int out_size, void* d_ws, size_t ws_size,
                              hipStream_t stream) {
  (void)in_sizes; (void)n_in; (void)out_size;
  const float* x   = (const float*)d_in[0];
  const float* Wf  = (const float*)d_in[1];
  const float* bf_ = (const float*)d_in[2];
  const float* Wi  = (const float*)d_in[3];
  const float* bi_ = (const float*)d_in[4];
  const float* Wo  = (const float*)d_in[5];
  const float* bo_ = (const float*)d_in[6];
  const float* Wc  = (const float*)d_in[7];
  const float* bc_ = (const float*)d_in[8];
  const float* h0  = (const float*)d_in[9];
  const float* c0  = (const float*)d_in[10];

  if (ws_size < WS_NEEDED) return;   // diagnostic fail, not a crash

  char* ws = (char*)d_ws;
  uint16_t* wp = (uint16_t*)(ws + WP_OFF);
  uint16_t* xp = (uint16_t*)(ws + XP_OFF);
  uint16_t* gx = (uint16_t*)(ws + GX_OFF);
  uint16_t* hs = (uint16_t*)(ws + HS_OFF);
  int* flags   = (int*)(ws + FL_OFF);

  hipMemsetAsync(flags, 0, 1024, stream);
  pack_w<<<9216, 256, 0, stream>>>(Wf, Wi, Wo, Wc, wp);
  pack_xg<<<24576, 256, 0, stream>>>(x, xp);
  pack_h0<<<48, 256, 0, stream>>>(h0, hs);
  gemm_gx<<<12288, 256, 0, stream>>>(wp, xp, gx);

  hipFuncSetAttribute(reinterpret_cast<const void*>(lstm_persist),
                      hipFuncAttributeMaxDynamicSharedMemorySize, PLDS_TOTAL);
  lstm_persist<<<NWG, 768, PLDS_TOTAL, stream>>>(bf_, bi_, bo_, bc_, c0,
                                                 wp, gx, hs, flags, (float*)d_out);
}